// Round 1
// baseline (1531.188 us; speedup 1.0000x reference)
//
#include <hip/hip_runtime.h>
#include <math.h>

#define NL 16
#define HASH_SIZE (1u << 19)
#define HASH_MASK (HASH_SIZE - 1u)
#define P1 2654435761u
#define P2 805459861u

struct Res16 { float r[NL]; };

__global__ __launch_bounds__(256) void hashenc_kernel(
    const float* __restrict__ x,
    const float* __restrict__ tables,
    float* __restrict__ out,
    int N, Res16 res)
{
    int n = blockIdx.x * 256 + threadIdx.x;
    if (n >= N) return;

    float px = x[3 * n + 0];
    float py = x[3 * n + 1];
    float pz = x[3 * n + 2];
    // jnp.clip(x, 0.0, 1.0 - 1e-6); 0.999999f is the f32 nearest to the f64 bound
    px = fminf(fmaxf(px, 0.0f), 0.999999f);
    py = fminf(fmaxf(py, 0.0f), 0.999999f);
    pz = fminf(fmaxf(pz, 0.0f), 0.999999f);

    float acc[2 * NL];

#pragma unroll
    for (int l = 0; l < NL; ++l) {
        const float r = res.r[l];
        float sx = px * r, sy = py * r, sz = pz * r;
        float fx = floorf(sx), fy = floorf(sy), fz = floorf(sz);
        float wx = sx - fx, wy = sy - fy, wz = sz - fz;
        unsigned ix = (unsigned)(int)fx;
        unsigned iy = (unsigned)(int)fy;
        unsigned iz = (unsigned)(int)fz;
        // per-dim hash partials: corner hash = hx ^ hy ^ hz, uint32 wrap exact
        unsigned hx0 = ix,         hx1 = ix + 1u;
        unsigned hy0 = iy * P1,    hy1 = hy0 + P1;
        unsigned hz0 = iz * P2,    hz1 = hz0 + P2;

        const float2* __restrict__ tb =
            reinterpret_cast<const float2*>(tables) + (size_t)l * HASH_SIZE;

        // issue all 8 gathers up front (independent -> stay in flight)
        float2 f000 = tb[(hx0 ^ hy0 ^ hz0) & HASH_MASK];
        float2 f001 = tb[(hx0 ^ hy0 ^ hz1) & HASH_MASK];
        float2 f010 = tb[(hx0 ^ hy1 ^ hz0) & HASH_MASK];
        float2 f011 = tb[(hx0 ^ hy1 ^ hz1) & HASH_MASK];
        float2 f100 = tb[(hx1 ^ hy0 ^ hz0) & HASH_MASK];
        float2 f101 = tb[(hx1 ^ hy0 ^ hz1) & HASH_MASK];
        float2 f110 = tb[(hx1 ^ hy1 ^ hz0) & HASH_MASK];
        float2 f111 = tb[(hx1 ^ hy1 ^ hz1) & HASH_MASK];

        float wx0 = 1.0f - wx, wy0 = 1.0f - wy, wz0 = 1.0f - wz;
        // corner weight = (cwx * cwy) * cwz, matching reference product order
        float c000 = (wx0 * wy0) * wz0, c001 = (wx0 * wy0) * wz;
        float c010 = (wx0 * wy ) * wz0, c011 = (wx0 * wy ) * wz;
        float c100 = (wx  * wy0) * wz0, c101 = (wx  * wy0) * wz;
        float c110 = (wx  * wy ) * wz0, c111 = (wx  * wy ) * wz;

        float a0 = c000 * f000.x + c001 * f001.x + c010 * f010.x + c011 * f011.x
                 + c100 * f100.x + c101 * f101.x + c110 * f110.x + c111 * f111.x;
        float a1 = c000 * f000.y + c001 * f001.y + c010 * f010.y + c011 * f011.y
                 + c100 * f100.y + c101 * f101.y + c110 * f110.y + c111 * f111.y;

        acc[2 * l + 0] = a0;
        acc[2 * l + 1] = a1;
    }

    // one full 128B row per thread -> 8x float4, every line fully written
    float4* o = reinterpret_cast<float4*>(out + (size_t)n * (2 * NL));
#pragma unroll
    for (int q = 0; q < 8; ++q) {
        o[q] = make_float4(acc[4 * q + 0], acc[4 * q + 1],
                           acc[4 * q + 2], acc[4 * q + 3]);
    }
}

extern "C" void kernel_launch(void* const* d_in, const int* in_sizes, int n_in,
                              void* d_out, int out_size, void* d_ws, size_t ws_size,
                              hipStream_t stream)
{
    const float* x      = (const float*)d_in[0];
    const float* tables = (const float*)d_in[1];
    float* out          = (float*)d_out;
    int N = in_sizes[0] / 3;

    // Replicate numpy's resolution computation bit-for-bit with glibc doubles:
    // _b = exp((log(512) - log(16)) / 15); res_i = int(ceil(16 * _b**i))
    // Levels 3/6/9/12/15 sit on exact ceil boundaries (b^3 == 2 in exact math),
    // so this MUST be computed, not hard-coded from a guessed table.
    Res16 res;
    double b = exp((log(512.0) - log(16.0)) / 15.0);
    for (int i = 0; i < NL; ++i) {
        res.r[i] = (float)(int)ceil(16.0 * pow(b, (double)i));
    }

    int grid = (N + 255) / 256;
    hipLaunchKernelGGL(hashenc_kernel, dim3(grid), dim3(256), 0, stream,
                       x, tables, out, N, res);
}